// Round 6
// baseline (204.113 us; speedup 1.0000x reference)
//
#include <hip/hip_runtime.h>

#define BB 4
#define NN 1024
#define MM 1024
#define DD 64
#define TILE 64

// Lane <-> m-column design:
//   - rhs[m0+lane, 0:64] pinned in 64 VGPRs (loaded once, global).
//   - lhs rows stream as wave-uniform LDS broadcast reads (conflict-free,
//     prefetchable, independent of the acc chain) -> no per-lane LDS operand
//     traffic in the loop (the r1..r5 bottleneck).
//   - out[n, m0:m0+64] written as ONE coalesced 256B store per n per wave.
// VALU floor: 2048 instr/thread -> 6.8 us at 4 blocks/CU.

__global__ __launch_bounds__(256, 4)
void SADSimilarity_38706245272206_kernel(const float* __restrict__ lhs,
                                         const float* __restrict__ rhs,
                                         float* __restrict__ out) {
    __shared__ float lt[TILE * DD];  // 16 KB, row-major, no pad needed (broadcast reads)

    const int b    = blockIdx.z;
    const int n0   = blockIdx.y * TILE;
    const int m0   = blockIdx.x * TILE;
    const int tid  = threadIdx.x;
    const int lane = tid & 63;
    const int w    = tid >> 6;   // wave id 0..3 -> n-rows [16w, 16w+16)

    // Issue rhs register loads first (long-latency global, 16 x dwordx4).
    const float* rrow = rhs + ((size_t)(b * MM + m0 + lane)) * DD;
    float4 rr[16];
    #pragma unroll
    for (int q = 0; q < 16; ++q) rr[q] = *(const float4*)(rrow + 4 * q);

    // Stage lhs 64x64 tile to LDS, coalesced: 1024 float4 / 256 threads.
    const float* lbase = lhs + ((size_t)(b * NN + n0)) * DD;
    #pragma unroll
    for (int p = 0; p < 4; ++p) {
        int idx = tid + p * 256;
        *(float4*)(&lt[idx * 4]) = *(const float4*)(lbase + idx * 4);
    }
    __syncthreads();

    float* obase = out + ((size_t)(b * NN + n0 + w * 16)) * MM + m0 + lane;

    for (int n = 0; n < 16; ++n) {
        const float* Lr = &lt[(w * 16 + n) * DD];
        float a0 = 0.f, a1 = 0.f, a2 = 0.f, a3 = 0.f;
        // unroll 4: operand window = 4 broadcast ds_read_b128 (16 VGPRs),
        // keeps total ~100 VGPRs (no spill at the 128-reg cap).
        #pragma unroll 4
        for (int q = 0; q < 16; ++q) {
            float4 lv = *(const float4*)(Lr + 4 * q);  // wave-uniform broadcast
            a0 += fabsf(rr[q].x - lv.x);
            a1 += fabsf(rr[q].y - lv.y);
            a2 += fabsf(rr[q].z - lv.z);
            a3 += fabsf(rr[q].w - lv.w);
        }
        obase[(size_t)n * MM] = -((a0 + a1) + (a2 + a3));  // coalesced 256B/wave
    }
}

extern "C" void kernel_launch(void* const* d_in, const int* in_sizes, int n_in,
                              void* d_out, int out_size, void* d_ws, size_t ws_size,
                              hipStream_t stream) {
    const float* lhs = (const float*)d_in[0];
    const float* rhs = (const float*)d_in[1];
    float* out = (float*)d_out;

    dim3 grid(MM / TILE, NN / TILE, BB);  // (16,16,4) = 1024 blocks -> 4 blocks/CU
    dim3 block(256, 1, 1);
    SADSimilarity_38706245272206_kernel<<<grid, block, 0, stream>>>(lhs, rhs, out);
}